// Round 4
// baseline (41.275 us; speedup 1.0000x reference)
//
#include <hip/hip_runtime.h>

typedef _Float16 half2_t __attribute__((ext_vector_type(2)));

#define G 512
#define N 24
#define DD 12288
#define DIM 64
#define HL 3

// One molecule per 64-lane wave. Lane j owns column j; the wave owns all 24
// atoms. h stays in registers across linear->aggregate (no LDS round-trip,
// no cross-wave barriers). x crosses lanes via a 3KB f16 LDS tile read as
// wave-uniform broadcast b128 (conflict-free by definition).
__global__ __launch_bounds__(64)
void gnn_mol_kernel(const int* __restrict__ fp,
                    const float* __restrict__ A,
                    const float* __restrict__ emb,
                    const float* __restrict__ W_fp,
                    const float* __restrict__ b_fp,
                    const float* __restrict__ W_out,
                    const float* __restrict__ b_out,
                    const float* __restrict__ W_prop,
                    const float* __restrict__ b_prop,
                    float* __restrict__ out)
{
    const int g = blockIdx.x;
    const int j = threadIdx.x;      // column 0..63

    __shared__ _Float16 xs[N][DIM]; // 3 KB: f16 copy of x for cross-lane reads
    __shared__ float    msh[DIM];
    __shared__ float    ysh[DIM];
    __shared__ float    zsh[DIM];

    const long srow = (long)g * N;
    const float* __restrict__ Abase = A + srow * (long)DD + srow; // wave-uniform

    // ---- embedding gather: x[a][j] = emb[fp[a]][j]; 24 loads in flight ----
    float xv[N];
    #pragma unroll
    for (int a = 0; a < N; ++a) {
        int f = fp[g * N + a];                 // uniform -> scalar load
        float v = emb[(long)f * DIM + j];      // coalesced 256B
        xv[a] = v;
        xs[a][j] = (_Float16)v;
    }
    __syncthreads();   // 1-wave block: compiles to waitcnt (+trivial barrier)

    #pragma unroll 1
    for (int layer = 0; layer < HL; ++layer) {
        // W row j (fp32 global, L1/L2-hot: same 16KB for all 512 blocks)
        const float* Wl = W_fp + layer * DIM * DIM + j * DIM;
        half2_t w2[32];
        #pragma unroll
        for (int k4 = 0; k4 < 16; ++k4) {
            float4 wv = *(const float4*)(Wl + 4 * k4);
            w2[2 * k4]     = __builtin_bit_cast(half2_t, __builtin_amdgcn_cvt_pkrtz(wv.x, wv.y));
            w2[2 * k4 + 1] = __builtin_bit_cast(half2_t, __builtin_amdgcn_cvt_pkrtz(wv.z, wv.w));
        }
        const float bias = b_fp[layer * DIM + j];

        // ---- linear: hreg[a] = relu(b[j] + sum_k x[a][k]*W[j][k]) ----
        float hreg[N];
        #pragma unroll
        for (int a = 0; a < N; ++a) {
            float acc0 = bias, acc1 = 0.f, acc2 = 0.f, acc3 = 0.f;
            #pragma unroll
            for (int q = 0; q < 8; ++q) {
                uint4 qv = *(const uint4*)(&xs[a][8 * q]);   // broadcast b128
                half2_t x0 = __builtin_bit_cast(half2_t, qv.x);
                half2_t x1 = __builtin_bit_cast(half2_t, qv.y);
                half2_t x2 = __builtin_bit_cast(half2_t, qv.z);
                half2_t x3 = __builtin_bit_cast(half2_t, qv.w);
                acc0 = __builtin_amdgcn_fdot2(x0, w2[4 * q + 0], acc0, false);
                acc1 = __builtin_amdgcn_fdot2(x1, w2[4 * q + 1], acc1, false);
                acc2 = __builtin_amdgcn_fdot2(x2, w2[4 * q + 2], acc2, false);
                acc3 = __builtin_amdgcn_fdot2(x3, w2[4 * q + 3], acc3, false);
            }
            hreg[a] = fmaxf((acc0 + acc1) + (acc2 + acc3), 0.f);
        }

        // ---- aggregate in registers: xv[a] += sum_b A[a][b] * hreg[b] ----
        // A rows are wave-uniform -> scalar (K$) loads; no LDS, no barrier.
        #pragma unroll
        for (int a = 0; a < N; ++a) {
            const float* __restrict__ Arow = Abase + (long)a * DD;
            float acc = 0.f;
            #pragma unroll
            for (int b = 0; b < N; ++b)
                acc = fmaf(Arow[b], hreg[b], acc);
            xv[a] += acc;
        }
        __syncthreads();                    // reads of old xs done (lockstep wave)
        #pragma unroll
        for (int a = 0; a < N; ++a)
            xs[a][j] = (_Float16)xv[a];     // publish x' for next layer
        __syncthreads();
    }

    // ---- segment sum entirely in registers: mol[j] = sum_a x[a][j] ----
    float mol = 0.f;
    #pragma unroll
    for (int a = 0; a < N; ++a) mol += xv[a];
    msh[j] = mol;
    __syncthreads();

    // ---- output MLP layer 0: ysh[j] = relu(b + sum_k W_out[j][k]*mol[k]) ----
    {
        float acc = b_out[j];
        const float* Wr = W_out + j * DIM;
        #pragma unroll
        for (int k4 = 0; k4 < 16; ++k4) {
            float4 mv = *(const float4*)(&msh[4 * k4]);      // broadcast
            acc += mv.x * Wr[4*k4+0] + mv.y * Wr[4*k4+1]
                 + mv.z * Wr[4*k4+2] + mv.w * Wr[4*k4+3];
        }
        ysh[j] = fmaxf(acc, 0.f);
    }
    __syncthreads();

    // ---- output MLP layer 1 ----
    {
        float acc = b_out[DIM + j];
        const float* Wr = W_out + DIM * DIM + j * DIM;
        #pragma unroll
        for (int k4 = 0; k4 < 16; ++k4) {
            float4 yv = *(const float4*)(&ysh[4 * k4]);      // broadcast
            acc += yv.x * Wr[4*k4+0] + yv.y * Wr[4*k4+1]
                 + yv.z * Wr[4*k4+2] + yv.w * Wr[4*k4+3];
        }
        zsh[j] = fmaxf(acc, 0.f);
    }
    __syncthreads();

    // ---- property head: out[g][p] = b_prop[p] + sum_k z[k]*W_prop[p][k] ----
    if (j < 2) {
        float acc = b_prop[j];
        const float* Wr = W_prop + j * DIM;
        #pragma unroll
        for (int k4 = 0; k4 < 16; ++k4) {
            float4 zv = *(const float4*)(&zsh[4 * k4]);
            acc += zv.x * Wr[4*k4+0] + zv.y * Wr[4*k4+1]
                 + zv.z * Wr[4*k4+2] + zv.w * Wr[4*k4+3];
        }
        out[g * 2 + j] = acc;
    }
}

extern "C" void kernel_launch(void* const* d_in, const int* in_sizes, int n_in,
                              void* d_out, int out_size, void* d_ws, size_t ws_size,
                              hipStream_t stream) {
    const int*   fp     = (const int*)  d_in[0];
    // d_in[1] segment_ids: implied by block index
    const float* A      = (const float*)d_in[2];
    const float* emb    = (const float*)d_in[3];
    const float* W_fp   = (const float*)d_in[4];
    const float* b_fp   = (const float*)d_in[5];
    const float* W_out  = (const float*)d_in[6];
    const float* b_out  = (const float*)d_in[7];
    const float* W_prop = (const float*)d_in[8];
    const float* b_prop = (const float*)d_in[9];
    float* out = (float*)d_out;

    gnn_mol_kernel<<<G, 64, 0, stream>>>(fp, A, emb, W_fp, b_fp,
                                         W_out, b_out, W_prop, b_prop, out);
}

// Round 5
// 25.044 us; speedup vs baseline: 1.6481x; 1.6481x over previous
//
#include <hip/hip_runtime.h>

typedef _Float16 half2_t __attribute__((ext_vector_type(2)));

#define G 512
#define N 24
#define DD 12288
#define DIM 64
#define HL 3

// 1 molecule per 256-thread block (4 waves x 6 atoms). Lane j = column j.
// Serial-chain minimized: W for all 3 layers preloaded to registers; xs is
// intra-wave only (no barriers); hs double-buffered -> 1 barrier per layer.
__global__ __launch_bounds__(256, 2)
void gnn_mol_kernel(const int* __restrict__ fp,
                    const float* __restrict__ A,
                    const float* __restrict__ emb,
                    const float* __restrict__ W_fp,
                    const float* __restrict__ b_fp,
                    const float* __restrict__ W_out,
                    const float* __restrict__ b_out,
                    const float* __restrict__ W_prop,
                    const float* __restrict__ b_prop,
                    float* __restrict__ out)
{
    const int g = blockIdx.x;
    const int t = threadIdx.x;
    const int j = t & 63;      // column 0..63
    const int w = t >> 6;      // wave 0..3; wave owns atoms w, w+4, ..., w+20

    __shared__ _Float16 xs[N][DIM];      // 3 KB   intra-wave lane exchange only
    __shared__ float    hs[2][N][DIM];   // 12 KB  double-buffered h
    __shared__ float    As[N * N];       // 2.25 KB adjacency block
    __shared__ float    ps[4][DIM];      // 1 KB   segsum partials
    __shared__ float    msh[DIM], ysh[DIM], zsh[DIM];

    // ---- stage A diagonal block (read after the layer-0 barrier) ----
    const long srow = (long)g * N;
    const float* __restrict__ Ag = A + srow * (long)DD + srow;
    for (int idx = t; idx < N * N; idx += 256) {
        int r = idx / N, c = idx - r * N;
        As[idx] = Ag[(long)r * DD + c];
    }

    // ---- preload + f16-convert ALL layers' W row j and biases (hoisted) ----
    half2_t w2[HL][32];
    float   bias[HL];
    #pragma unroll
    for (int l = 0; l < HL; ++l) {
        const float* Wl = W_fp + l * DIM * DIM + j * DIM;
        #pragma unroll
        for (int k4 = 0; k4 < 16; ++k4) {
            float4 wv = *(const float4*)(Wl + 4 * k4);
            w2[l][2*k4]   = __builtin_bit_cast(half2_t, __builtin_amdgcn_cvt_pkrtz(wv.x, wv.y));
            w2[l][2*k4+1] = __builtin_bit_cast(half2_t, __builtin_amdgcn_cvt_pkrtz(wv.z, wv.w));
        }
        bias[l] = b_fp[l * DIM + j];
    }

    // ---- embedding gather: x[a][j] = emb[fp[a]][j] ----
    float xv[6];
    #pragma unroll
    for (int r = 0; r < 6; ++r) {
        int a = w + 4 * r;
        int f = fp[g * N + a];                 // wave-uniform -> s_load
        float v = emb[(long)f * DIM + j];      // coalesced 256B/wave
        xv[r] = v;
        xs[a][j] = (_Float16)v;                // own-wave publish (lgkmcnt only)
    }

    // ---- 3 message-passing rounds, ONE barrier each ----
    #pragma unroll
    for (int l = 0; l < HL; ++l) {
        // linear: h[a][j] = relu(b[j] + sum_k x[a][k] * W[j][k])  (dot2)
        #pragma unroll
        for (int r = 0; r < 6; ++r) {
            int a = w + 4 * r;
            float acc0 = bias[l], acc1 = 0.f, acc2 = 0.f, acc3 = 0.f;
            #pragma unroll
            for (int q = 0; q < 8; ++q) {
                uint4 qv = *(const uint4*)(&xs[a][8 * q]);   // broadcast b128
                half2_t x0 = __builtin_bit_cast(half2_t, qv.x);
                half2_t x1 = __builtin_bit_cast(half2_t, qv.y);
                half2_t x2 = __builtin_bit_cast(half2_t, qv.z);
                half2_t x3 = __builtin_bit_cast(half2_t, qv.w);
                acc0 = __builtin_amdgcn_fdot2(x0, w2[l][4*q+0], acc0, false);
                acc1 = __builtin_amdgcn_fdot2(x1, w2[l][4*q+1], acc1, false);
                acc2 = __builtin_amdgcn_fdot2(x2, w2[l][4*q+2], acc2, false);
                acc3 = __builtin_amdgcn_fdot2(x3, w2[l][4*q+3], acc3, false);
            }
            hs[l & 1][a][j] = fmaxf((acc0 + acc1) + (acc2 + acc3), 0.f);
        }
        __syncthreads();   // h publish (covers As staging on l==0)

        // h column j -> regs (24x ds_read_b32, 2-way/free)
        float hcol[N];
        #pragma unroll
        for (int b = 0; b < N; ++b) hcol[b] = hs[l & 1][b][j];

        // aggregate: xv[a] += sum_b A[a][b] * h[b][j]; A rows broadcast b128
        #pragma unroll
        for (int r = 0; r < 6; ++r) {
            int a = w + 4 * r;
            float acc = 0.f;
            #pragma unroll
            for (int b4 = 0; b4 < 6; ++b4) {
                float4 av = *(const float4*)(&As[a * N + 4 * b4]);
                acc += av.x * hcol[4*b4+0] + av.y * hcol[4*b4+1]
                     + av.z * hcol[4*b4+2] + av.w * hcol[4*b4+3];
            }
            xv[r] += acc;
            xs[a][j] = (_Float16)xv[r];   // own-wave publish, NO barrier
        }
        // no barrier: next layer's h targets the other hs buffer
    }

    // ---- segment sum partials ----
    ps[w][j] = ((xv[0] + xv[1]) + (xv[2] + xv[3])) + (xv[4] + xv[5]);
    __syncthreads();

    // ---- entire output MLP inside wave 0 (no more barriers) ----
    if (t < DIM) {
        float m = (ps[0][t] + ps[1][t]) + (ps[2][t] + ps[3][t]);
        msh[t] = m;                        // intra-wave publish

        float acc = b_out[t];
        const float* Wr0 = W_out + t * DIM;
        #pragma unroll
        for (int k4 = 0; k4 < 16; ++k4) {
            float4 mv = *(const float4*)(&msh[4 * k4]);      // broadcast
            acc += mv.x * Wr0[4*k4+0] + mv.y * Wr0[4*k4+1]
                 + mv.z * Wr0[4*k4+2] + mv.w * Wr0[4*k4+3];
        }
        ysh[t] = fmaxf(acc, 0.f);          // intra-wave publish

        float acc2 = b_out[DIM + t];
        const float* Wr1 = W_out + DIM * DIM + t * DIM;
        #pragma unroll
        for (int k4 = 0; k4 < 16; ++k4) {
            float4 yv = *(const float4*)(&ysh[4 * k4]);      // broadcast
            acc2 += yv.x * Wr1[4*k4+0] + yv.y * Wr1[4*k4+1]
                  + yv.z * Wr1[4*k4+2] + yv.w * Wr1[4*k4+3];
        }
        zsh[t] = fmaxf(acc2, 0.f);         // intra-wave publish

        if (t < 2) {
            float acc3 = b_prop[t];
            const float* Wr2 = W_prop + t * DIM;
            #pragma unroll
            for (int k4 = 0; k4 < 16; ++k4) {
                float4 zv = *(const float4*)(&zsh[4 * k4]);
                acc3 += zv.x * Wr2[4*k4+0] + zv.y * Wr2[4*k4+1]
                      + zv.z * Wr2[4*k4+2] + zv.w * Wr2[4*k4+3];
            }
            out[g * 2 + t] = acc3;
        }
    }
}

extern "C" void kernel_launch(void* const* d_in, const int* in_sizes, int n_in,
                              void* d_out, int out_size, void* d_ws, size_t ws_size,
                              hipStream_t stream) {
    const int*   fp     = (const int*)  d_in[0];
    // d_in[1] segment_ids: implied by block index
    const float* A      = (const float*)d_in[2];
    const float* emb    = (const float*)d_in[3];
    const float* W_fp   = (const float*)d_in[4];
    const float* b_fp   = (const float*)d_in[5];
    const float* W_out  = (const float*)d_in[6];
    const float* b_out  = (const float*)d_in[7];
    const float* W_prop = (const float*)d_in[8];
    const float* b_prop = (const float*)d_in[9];
    float* out = (float*)d_out;

    gnn_mol_kernel<<<G, 256, 0, stream>>>(fp, A, emb, W_fp, b_fp,
                                          W_out, b_out, W_prop, b_prop, out);
}

// Round 6
// 14.091 us; speedup vs baseline: 2.9292x; 1.7773x over previous
//
#include <hip/hip_runtime.h>

#define G 512
#define N 24
#define DD 12288
#define DIM 64

typedef __fp16 f16x2 __attribute__((ext_vector_type(2)));
typedef __fp16 f16x4 __attribute__((ext_vector_type(4)));
typedef __fp16 f16x8 __attribute__((ext_vector_type(8)));
typedef float  f32x4 __attribute__((ext_vector_type(4)));

#define XSTR 72   // halves per X row (32 rows); 144B stride, 16B-aligned frags
#define HSTR 36   // halves per H column (col-major [64][36]); 72B stride, 8B-aligned

union PkU { f16x8 v; f16x4 q[2]; f16x2 h2[4]; };

static __device__ __forceinline__ f16x8 pack8(float4 a, float4 b) {
    PkU u;
    u.h2[0] = __builtin_amdgcn_cvt_pkrtz(a.x, a.y);
    u.h2[1] = __builtin_amdgcn_cvt_pkrtz(a.z, a.w);
    u.h2[2] = __builtin_amdgcn_cvt_pkrtz(b.x, b.y);
    u.h2[3] = __builtin_amdgcn_cvt_pkrtz(b.z, b.w);
    return u.v;
}

// One molecule per 64-lane wave (block = 1 wave, ZERO barriers).
// GEMM1: H(32x64) = relu(X @ W^T + b)  via mfma 16x16x32 f16 (2Mt x 4Nt x 2K)
// GEMM2: X'(32x64) = X + A24 @ H       via mfma (2Mt x 4Nt x 1K), X as C-in regs
__global__ __launch_bounds__(64, 2)
void gnn_wave_kernel(const int* __restrict__ fp,
                     const float* __restrict__ A,
                     const float* __restrict__ emb,
                     const float* __restrict__ W_fp,
                     const float* __restrict__ b_fp,
                     const float* __restrict__ W_out,
                     const float* __restrict__ b_out,
                     const float* __restrict__ W_prop,
                     const float* __restrict__ b_prop,
                     float* __restrict__ out)
{
    const int l  = threadIdx.x;   // lane 0..63
    const int p  = l & 15;        // frag row/col index
    const int q4 = l >> 4;        // frag k-group / row-group
    const int gq = blockIdx.x;
    const long srow = (long)gq * N;

    __shared__ __align__(16) __fp16 Xl[32 * XSTR];  // 4.5 KB row-major X (f16 copy)
    __shared__ __align__(16) __fp16 Hl[64 * HSTR];  // 4.5 KB col-major H
    __shared__ float molv[DIM];
    __shared__ float ybuf[DIM];

    // ---- preload W fragments (all 3 layers) + biases into registers ----
    // B-frag: lane holds W^T[k][c] = W[c][k], c=16nt+p, k=32s+8q4+i (k-contig in W row)
    f16x8 wf[3][4][2];
    float bias[3][4];
    #pragma unroll
    for (int lyr = 0; lyr < 3; ++lyr) {
        #pragma unroll
        for (int nt = 0; nt < 4; ++nt) {
            bias[lyr][nt] = b_fp[lyr * DIM + 16 * nt + p];
            #pragma unroll
            for (int s = 0; s < 2; ++s) {
                const float* src = W_fp + lyr * DIM * DIM + (16 * nt + p) * DIM + 32 * s + 8 * q4;
                wf[lyr][nt][s] = pack8(*(const float4*)src, *(const float4*)(src + 4));
            }
        }
    }

    // ---- preload A24 fragments (layer-invariant); zero-mask rows/k >= 24 ----
    // A-frag: lane holds A24[r][k], r=16mt+p, k=8q4+i
    f16x8 a24[2];
    #pragma unroll
    for (int mt = 0; mt < 2; ++mt) {
        int r = 16 * mt + p;
        if (r < N && q4 < 3) {
            const float* src = A + (srow + r) * (long)DD + srow + 8 * q4;
            a24[mt] = pack8(*(const float4*)src, *(const float4*)(src + 4));
        } else {
            f16x8 z = { (__fp16)0, (__fp16)0, (__fp16)0, (__fp16)0,
                        (__fp16)0, (__fp16)0, (__fp16)0, (__fp16)0 };
            a24[mt] = z;
        }
    }

    // ---- embedding: X[a][l] = emb[fp[a]][l]; zero pad rows 24..31 ----
    #pragma unroll
    for (int a = 0; a < N; ++a) {
        int f = fp[gq * N + a];                       // uniform -> s_load
        float v = emb[(long)f * DIM + l];             // coalesced 256B
        Xl[a * XSTR + l] = (__fp16)v;
    }
    #pragma unroll
    for (int r = N; r < 32; ++r) Xl[r * XSTR + l] = (__fp16)0;

    // ---- f32 master X in C-fragment layout: row=16mt+4q4+reg, col=16nt+p ----
    f32x4 xacc[2][4];
    #pragma unroll
    for (int mt = 0; mt < 2; ++mt)
        #pragma unroll
        for (int nt = 0; nt < 4; ++nt)
            #pragma unroll
            for (int reg = 0; reg < 4; ++reg)
                xacc[mt][nt][reg] =
                    (float)Xl[(16 * mt + 4 * q4 + reg) * XSTR + 16 * nt + p];

    // ---- 3 message-passing layers, barrier-free ----
    #pragma unroll
    for (int lyr = 0; lyr < 3; ++lyr) {
        // GEMM1: acc = bias (C-in) + X @ W^T
        f32x4 acc[2][4];
        #pragma unroll
        for (int mt = 0; mt < 2; ++mt)
            #pragma unroll
            for (int nt = 0; nt < 4; ++nt) {
                float b = bias[lyr][nt];
                acc[mt][nt] = (f32x4){ b, b, b, b };
            }
        #pragma unroll
        for (int s = 0; s < 2; ++s) {
            // A-frags from Xl: row=16mt+p, k=32s+8q4+i (contig halves, 16B aligned)
            f16x8 xa0 = *(const f16x8*)(&Xl[(p) * XSTR + 32 * s + 8 * q4]);
            f16x8 xa1 = *(const f16x8*)(&Xl[(16 + p) * XSTR + 32 * s + 8 * q4]);
            #pragma unroll
            for (int nt = 0; nt < 4; ++nt) {
                acc[0][nt] = __builtin_amdgcn_mfma_f32_16x16x32_f16(xa0, wf[lyr][nt][s], acc[0][nt], 0, 0, 0);
                acc[1][nt] = __builtin_amdgcn_mfma_f32_16x16x32_f16(xa1, wf[lyr][nt][s], acc[1][nt], 0, 0, 0);
            }
        }

        // relu -> H store, col-major [c][r]: 4 consecutive rows pack to one b64
        #pragma unroll
        for (int mt = 0; mt < 2; ++mt)
            #pragma unroll
            for (int nt = 0; nt < 4; ++nt) {
                float h0 = fmaxf(acc[mt][nt][0], 0.f);
                float h1 = fmaxf(acc[mt][nt][1], 0.f);
                float h2 = fmaxf(acc[mt][nt][2], 0.f);
                float h3 = fmaxf(acc[mt][nt][3], 0.f);
                PkU u;
                u.h2[0] = __builtin_amdgcn_cvt_pkrtz(h0, h1);
                u.h2[1] = __builtin_amdgcn_cvt_pkrtz(h2, h3);
                *(f16x4*)(&Hl[(16 * nt + p) * HSTR + 16 * mt + 4 * q4]) = u.q[0];
            }

        // GEMM2: xacc += A24 @ H   (B-frag: H[k][c] from col-major Hl, k=8q4+i)
        #pragma unroll
        for (int nt = 0; nt < 4; ++nt) {
            PkU hb;
            hb.q[0] = *(const f16x4*)(&Hl[(16 * nt + p) * HSTR + 8 * q4]);
            hb.q[1] = *(const f16x4*)(&Hl[(16 * nt + p) * HSTR + 8 * q4 + 4]);
            #pragma unroll
            for (int mt = 0; mt < 2; ++mt)
                xacc[mt][nt] = __builtin_amdgcn_mfma_f32_16x16x32_f16(a24[mt], hb.v, xacc[mt][nt], 0, 0, 0);
        }

        // publish X' (f16) for next layer's GEMM1 (skip after last layer)
        if (lyr < 2) {
            #pragma unroll
            for (int mt = 0; mt < 2; ++mt)
                #pragma unroll
                for (int nt = 0; nt < 4; ++nt)
                    #pragma unroll
                    for (int reg = 0; reg < 4; ++reg)
                        Xl[(16 * mt + 4 * q4 + reg) * XSTR + 16 * nt + p] =
                            (__fp16)xacc[mt][nt][reg];
        }
    }

    // ---- segment sum: mol[c] = sum_{r<24} X[r][c]; reduce over q4 groups ----
    #pragma unroll
    for (int nt = 0; nt < 4; ++nt) {
        float part = xacc[0][nt][0] + xacc[0][nt][1] + xacc[0][nt][2] + xacc[0][nt][3];
        float part1 = xacc[1][nt][0] + xacc[1][nt][1] + xacc[1][nt][2] + xacc[1][nt][3];
        part += (q4 < 2) ? part1 : 0.f;   // rows 16..23 only (24..31 are pad)
        part += __shfl_xor(part, 16, 64);
        part += __shfl_xor(part, 32, 64);
        if (l < 16) molv[16 * nt + l] = part;
    }

    // ---- output MLP layer 0 (lane = output unit) ----
    float accy = b_out[l];
    {
        const float* Wr = W_out + l * DIM;
        #pragma unroll
        for (int k4 = 0; k4 < 16; ++k4) {
            float4 wv = *(const float4*)(Wr + 4 * k4);
            float4 mv = *(const float4*)(&molv[4 * k4]);    // uniform broadcast
            accy += wv.x * mv.x + wv.y * mv.y + wv.z * mv.z + wv.w * mv.w;
        }
    }
    ybuf[l] = fmaxf(accy, 0.f);

    // ---- output MLP layer 1 ----
    float accz = b_out[DIM + l];
    {
        const float* Wr = W_out + DIM * DIM + l * DIM;
        #pragma unroll
        for (int k4 = 0; k4 < 16; ++k4) {
            float4 wv = *(const float4*)(Wr + 4 * k4);
            float4 yv = *(const float4*)(&ybuf[4 * k4]);    // uniform broadcast
            accz += wv.x * yv.x + wv.y * yv.y + wv.z * yv.z + wv.w * yv.w;
        }
    }
    float z = fmaxf(accz, 0.f);

    // ---- property head: butterfly reduce z . W_prop[p] across the wave ----
    float t0 = z * W_prop[l];
    float t1 = z * W_prop[DIM + l];
    #pragma unroll
    for (int off = 1; off < 64; off <<= 1) {
        t0 += __shfl_xor(t0, off, 64);
        t1 += __shfl_xor(t1, off, 64);
    }
    if (l == 0) {
        out[gq * 2 + 0] = t0 + b_prop[0];
        out[gq * 2 + 1] = t1 + b_prop[1];
    }
}

extern "C" void kernel_launch(void* const* d_in, const int* in_sizes, int n_in,
                              void* d_out, int out_size, void* d_ws, size_t ws_size,
                              hipStream_t stream) {
    const int*   fp     = (const int*)  d_in[0];
    // d_in[1] segment_ids: implied by block index
    const float* A      = (const float*)d_in[2];
    const float* emb    = (const float*)d_in[3];
    const float* W_fp   = (const float*)d_in[4];
    const float* b_fp   = (const float*)d_in[5];
    const float* W_out  = (const float*)d_in[6];
    const float* b_out  = (const float*)d_in[7];
    const float* W_prop = (const float*)d_in[8];
    const float* b_prop = (const float*)d_in[9];
    float* out = (float*)d_out;

    gnn_wave_kernel<<<G, 64, 0, stream>>>(fp, A, emb, W_fp, b_fp,
                                          W_out, b_out, W_prop, b_prop, out);
}

// Round 7
// 12.412 us; speedup vs baseline: 3.3254x; 1.1353x over previous
//
#include <hip/hip_runtime.h>

#define G 512
#define N 24
#define DD 12288
#define DIM 64

typedef __fp16 f16x2 __attribute__((ext_vector_type(2)));
typedef __fp16 f16x4 __attribute__((ext_vector_type(4)));
typedef __fp16 f16x8 __attribute__((ext_vector_type(8)));
typedef float  f32x4 __attribute__((ext_vector_type(4)));

#define XSTR 72   // halves per X row: 144 B (16B multiple)
#define HSTR 40   // halves per H unit-row: 80 B (16B multiple)

union PkU { f16x8 v; f16x4 q[2]; f16x2 h2[4]; };

static __device__ __forceinline__ f16x8 pack8(float4 a, float4 b) {
    PkU u;
    u.h2[0] = __builtin_amdgcn_cvt_pkrtz(a.x, a.y);
    u.h2[1] = __builtin_amdgcn_cvt_pkrtz(a.z, a.w);
    u.h2[2] = __builtin_amdgcn_cvt_pkrtz(b.x, b.y);
    u.h2[3] = __builtin_amdgcn_cvt_pkrtz(b.z, b.w);
    return u.v;
}

// One molecule per 256-thread block; wave wv owns unit columns 16wv..16wv+15.
// GEMM1 (H = X @ W^T + b): per wave 2Mt x 1Nt x 2K = 4 MFMA.
// GEMM2 (X' = X + A24 @ H): column-separable -> H is wave-private; 2 MFMA.
// Only X' crosses waves: ping-pong Xl buffer, ONE barrier per layer.
__global__ __launch_bounds__(256, 2)
void gnn_kernel(const int* __restrict__ fp,
                const float* __restrict__ A,
                const float* __restrict__ emb,
                const float* __restrict__ W_fp,
                const float* __restrict__ b_fp,
                const float* __restrict__ W_out,
                const float* __restrict__ b_out,
                const float* __restrict__ W_prop,
                const float* __restrict__ b_prop,
                float* __restrict__ out)
{
    const int t  = threadIdx.x;
    const int l  = t & 63;
    const int wv = t >> 6;     // 0..3: unit-tile owner
    const int p  = l & 15;
    const int q4 = l >> 4;
    const int gq = blockIdx.x;
    const long srow = (long)gq * N;

    __shared__ __align__(16) __fp16 Xl[2][32][XSTR];  // 9.2 KB ping-pong X (f16)
    __shared__ __align__(16) __fp16 Hl[4][16][HSTR];  // 5.1 KB per-wave H
    __shared__ float molv[DIM];
    __shared__ float ybuf[DIM];

    // ---- embedding -> Xl[0]: wave wv loads atoms 6wv..6wv+5; zero pad rows ----
    #pragma unroll
    for (int i = 0; i < 6; ++i) {
        int a = 6 * wv + i;
        int f = fp[gq * N + a];                    // wave-uniform -> s_load
        Xl[0][a][l] = (__fp16)emb[(long)f * DIM + l];
    }
    Xl[0][24 + 2 * wv][l] = (__fp16)0.f;
    Xl[0][25 + 2 * wv][l] = (__fp16)0.f;

    // ---- A24 fragments (A-op: row = 16mt+p, k = 8q4+i), zero-masked pad ----
    f16x8 a24[2];
    #pragma unroll
    for (int mt = 0; mt < 2; ++mt) {
        int r = 16 * mt + p;
        if (r < N && q4 < 3) {
            const float* src = A + (srow + r) * (long)DD + srow + 8 * q4;
            a24[mt] = pack8(*(const float4*)src, *(const float4*)(src + 4));
        } else {
            f16x8 z = { (__fp16)0, (__fp16)0, (__fp16)0, (__fp16)0,
                        (__fp16)0, (__fp16)0, (__fp16)0, (__fp16)0 };
            a24[mt] = z;
        }
    }

    // ---- W fragments + biases, own 16-unit tile only (B-op: col=p, k=32s+8q4+i) ----
    f16x8 wf[3][2];
    float bias[3];
    #pragma unroll
    for (int lyr = 0; lyr < 3; ++lyr) {
        #pragma unroll
        for (int s = 0; s < 2; ++s) {
            const float* src = W_fp + lyr * DIM * DIM + (16 * wv + p) * DIM + 32 * s + 8 * q4;
            wf[lyr][s] = pack8(*(const float4*)src, *(const float4*)(src + 4));
        }
        bias[lyr] = b_fp[lyr * DIM + 16 * wv + p];
    }

    __syncthreads();   // X complete

    // ---- f32 master X in C-layout: row = 16mt+4q4+reg, col = 16wv+p ----
    f32x4 xacc[2];
    #pragma unroll
    for (int mt = 0; mt < 2; ++mt)
        #pragma unroll
        for (int reg = 0; reg < 4; ++reg)
            xacc[mt][reg] = (float)Xl[0][16 * mt + 4 * q4 + reg][16 * wv + p];

    // ---- 3 message-passing layers, one barrier each ----
    #pragma unroll
    for (int lyr = 0; lyr < 3; ++lyr) {
        const int cur = lyr & 1;

        f32x4 acc0 = { bias[lyr], bias[lyr], bias[lyr], bias[lyr] };
        f32x4 acc1 = acc0;
        #pragma unroll
        for (int s = 0; s < 2; ++s) {
            f16x8 xa0 = *(const f16x8*)(&Xl[cur][p][32 * s + 8 * q4]);
            f16x8 xa1 = *(const f16x8*)(&Xl[cur][16 + p][32 * s + 8 * q4]);
            acc0 = __builtin_amdgcn_mfma_f32_16x16x32_f16(xa0, wf[lyr][s], acc0, 0, 0, 0);
            acc1 = __builtin_amdgcn_mfma_f32_16x16x32_f16(xa1, wf[lyr][s], acc1, 0, 0, 0);
        }

        // relu -> wave-private Hl[wv][unit p][atom]: packed b64 stores
        {
            PkU u0, u1;
            u0.h2[0] = __builtin_amdgcn_cvt_pkrtz(fmaxf(acc0[0], 0.f), fmaxf(acc0[1], 0.f));
            u0.h2[1] = __builtin_amdgcn_cvt_pkrtz(fmaxf(acc0[2], 0.f), fmaxf(acc0[3], 0.f));
            u1.h2[0] = __builtin_amdgcn_cvt_pkrtz(fmaxf(acc1[0], 0.f), fmaxf(acc1[1], 0.f));
            u1.h2[1] = __builtin_amdgcn_cvt_pkrtz(fmaxf(acc1[2], 0.f), fmaxf(acc1[3], 0.f));
            *(f16x4*)(&Hl[wv][p][4 * q4])      = u0.q[0];   // atoms 4q4..4q4+3
            *(f16x4*)(&Hl[wv][p][16 + 4 * q4]) = u1.q[0];   // atoms 16+4q4..+3
        }

        // GEMM2 (intra-wave): B-frag = H[k=8q4+i][col p] contiguous b128
        f16x8 hb = *(const f16x8*)(&Hl[wv][p][8 * q4]);
        xacc[0] = __builtin_amdgcn_mfma_f32_16x16x32_f16(a24[0], hb, xacc[0], 0, 0, 0);
        xacc[1] = __builtin_amdgcn_mfma_f32_16x16x32_f16(a24[1], hb, xacc[1], 0, 0, 0);

        // publish X' (own cols) into the other buffer; barrier
        if (lyr < 2) {
            const int nxt = cur ^ 1;
            #pragma unroll
            for (int mt = 0; mt < 2; ++mt)
                #pragma unroll
                for (int reg = 0; reg < 4; ++reg)
                    Xl[nxt][16 * mt + 4 * q4 + reg][16 * wv + p] = (__fp16)xacc[mt][reg];
            __syncthreads();
        }
    }

    // ---- segment sum (pad rows are exactly 0 -> unconditional) ----
    float part = (xacc[0][0] + xacc[0][1]) + (xacc[0][2] + xacc[0][3])
               + (xacc[1][0] + xacc[1][1]) + (xacc[1][2] + xacc[1][3]);
    part += __shfl_xor(part, 16, 64);
    part += __shfl_xor(part, 32, 64);
    if (l < 16) molv[16 * wv + l] = part;
    __syncthreads();

    // ---- output MLP + property head, wave 0 only ----
    if (t < DIM) {
        float accy = b_out[t];
        const float* Wr0 = W_out + t * DIM;
        #pragma unroll
        for (int k4 = 0; k4 < 16; ++k4) {
            float4 wr = *(const float4*)(Wr0 + 4 * k4);
            float4 mv = *(const float4*)(&molv[4 * k4]);   // uniform broadcast
            accy += wr.x * mv.x + wr.y * mv.y + wr.z * mv.z + wr.w * mv.w;
        }
        ybuf[t] = fmaxf(accy, 0.f);

        float accz = b_out[DIM + t];
        const float* Wr1 = W_out + DIM * DIM + t * DIM;
        #pragma unroll
        for (int k4 = 0; k4 < 16; ++k4) {
            float4 wr = *(const float4*)(Wr1 + 4 * k4);
            float4 yv = *(const float4*)(&ybuf[4 * k4]);   // uniform broadcast
            accz += wr.x * yv.x + wr.y * yv.y + wr.z * yv.z + wr.w * yv.w;
        }
        float z = fmaxf(accz, 0.f);

        float t0 = z * W_prop[t];
        float t1 = z * W_prop[DIM + t];
        #pragma unroll
        for (int off = 1; off < 64; off <<= 1) {
            t0 += __shfl_xor(t0, off, 64);
            t1 += __shfl_xor(t1, off, 64);
        }
        if (t == 0) {
            out[gq * 2 + 0] = t0 + b_prop[0];
            out[gq * 2 + 1] = t1 + b_prop[1];
        }
    }
}

extern "C" void kernel_launch(void* const* d_in, const int* in_sizes, int n_in,
                              void* d_out, int out_size, void* d_ws, size_t ws_size,
                              hipStream_t stream) {
    const int*   fp     = (const int*)  d_in[0];
    // d_in[1] segment_ids: implied by block index
    const float* A      = (const float*)d_in[2];
    const float* emb    = (const float*)d_in[3];
    const float* W_fp   = (const float*)d_in[4];
    const float* b_fp   = (const float*)d_in[5];
    const float* W_out  = (const float*)d_in[6];
    const float* b_out  = (const float*)d_in[7];
    const float* W_prop = (const float*)d_in[8];
    const float* b_prop = (const float*)d_in[9];
    float* outp = (float*)d_out;

    gnn_kernel<<<G, 256, 0, stream>>>(fp, A, emb, W_fp, b_fp,
                                      W_out, b_out, W_prop, b_prop, outp);
}